// Round 1
// baseline (150.079 us; speedup 1.0000x reference)
//
#include <hip/hip_runtime.h>
#include <hip/hip_bf16.h>
#include <stdint.h>

typedef __attribute__((ext_vector_type(8))) short bf16x8;
typedef __attribute__((ext_vector_type(4))) float f32x4;
typedef __attribute__((ext_vector_type(4))) unsigned short u16x4;

__device__ __forceinline__ float silu_f(float x) {
    return x * __builtin_amdgcn_rcpf(1.0f + __expf(-x));
}

// round-to-nearest-even f32 -> bf16
__device__ __forceinline__ unsigned short f2bf(float x) {
    union { float f; unsigned int u; } v; v.f = x;
    unsigned int r = v.u + 0x7fffu + ((v.u >> 16) & 1u);
    return (unsigned short)(r >> 16);
}
__device__ __forceinline__ float bf2f(unsigned short u) {
    union { unsigned int u; float f; } v; v.u = ((unsigned int)u) << 16;
    return v.f;
}

// async global->LDS, 16B per lane. LDS dest = wave-uniform base + lane*16.
__device__ __forceinline__ void async16(void* l, const void* g) {
    auto lds3 = (__attribute__((address_space(3))) unsigned int*)(uintptr_t)l;
    auto g1   = (const __attribute__((address_space(1))) unsigned int*)(uintptr_t)g;
    __builtin_amdgcn_global_load_lds(g1, lds3, 16, 0, 0);
}

// Precompute:
//   P1[t][o] = sum_k table[t][k] * W[k][o]       + b[o]   (bf16)
//   P2[t][o] = sum_k table[t][k] * W[128+k][o]            (bf16)
//   Wt3[o][k] = W[256+k][o]                               (bf16, transposed)
__global__ void prep_P(const int* __restrict__ code_idx,
                       const float* __restrict__ codebook,
                       const float* __restrict__ W,
                       const float* __restrict__ b,
                       unsigned short* __restrict__ P1,
                       unsigned short* __restrict__ P2,
                       unsigned short* __restrict__ Wt3)
{
    __shared__ float trow[128];
    const int t = blockIdx.x, tid = threadIdx.x;
    if (tid < 128) {
        int sym = code_idx[t * 8 + (tid >> 4)];
        trow[tid] = codebook[sym * 16 + (tid & 15)];
    } else {
        int k = tid - 128;                       // 0..127
        Wt3[t * 128 + k] = f2bf(W[(256 + k) * 128 + t]);
    }
    __syncthreads();
    const int which = tid >> 7, o = tid & 127;
    const float* Wb = W + which * 16384;
    float acc = which ? 0.0f : b[o];
#pragma unroll 8
    for (int k = 0; k < 128; ++k)
        acc += trow[k] * Wb[k * 128 + o];
    (which ? P2 : P1)[t * 128 + o] = f2bf(acc);
}

// Fused main, 64 edges per block, 256 threads (4 waves, 32x64 C-tile each):
//   lB = Wt3 (128x128 bf16, K=128), async16-staged, chunk-swizzled
//   lR = rbf tile (64 x 24B), async16-staged
//   lA = r = silu(rbf @ W_rbf + b_rbf) bf16, VALU-computed from lR
//   C^T = B @ A^T via SWAPPED mfma operands (A/B operand layouts are
//   symmetric, so swapping args transposes D): each lane then owns one
//   edge x 4 consecutive output cols per tile -> float4 stores, ushort4
//   P-gathers, 4x fewer VMEM instructions in the epilogue.
__global__ __launch_bounds__(256, 3) void fused_main(
    const int* __restrict__ x,
    const float* __restrict__ rbf,
    const int* __restrict__ ei,
    const int* __restrict__ ej,
    const float* __restrict__ W_rbf,
    const float* __restrict__ b_rbf,
    const unsigned short* __restrict__ P1,
    const unsigned short* __restrict__ P2,
    const unsigned short* __restrict__ Wt3,
    float* __restrict__ out)
{
    __shared__ __align__(16) unsigned char lB[32768];  // Wt3 [128 rows][256B]
    __shared__ __align__(16) unsigned char lA[16384];  // r   [64 rows][256B]
    __shared__ __align__(16) unsigned char lR[1536];   // rbf [64 rows][24B]

    const int tid  = threadIdx.x;
    const int lane = tid & 63;
    const int w    = tid >> 6;
    const int e0   = blockIdx.x * 64;

    const int quad = lane >> 4, l15 = lane & 15;
    const int wm = (w >> 1) * 32, wn = (w & 1) * 64;

    // ---- phase 0: async stages + index chase ----
    {   // B: physical chunk ch holds logical chunk ch ^ (o&7)
        const int ri = lane >> 4, ch = lane & 15;
#pragma unroll
        for (int rr = 0; rr < 8; ++rr) {
            int g = w * 8 + rr;           // 4-row group 0..31
            int o = g * 4 + ri;
            int j = ch ^ (o & 7);
            async16(lB + g * 1024, Wt3 + o * 128 + j * 8);
        }
    }
    // rbf tile: 1536B contiguous
    if (w == 0)
        async16(lR, (const unsigned char*)rbf + (size_t)e0 * 24 + lane * 16);
    else if (w == 1 && lane < 32)
        async16(lR + 1024, (const unsigned char*)rbf + (size_t)e0 * 24 + 1024 + lane * 16);

    // epilogue row indices: lane (l15) owns edge wm+mi*16+l15 (same for all
    // quads) -> only 2 chases per thread per table
    int ti[2], tj[2];
#pragma unroll
    for (int mi = 0; mi < 2; ++mi) {
        int e = e0 + wm + mi * 16 + l15;
        ti[mi] = x[ei[e]];
        tj[mi] = x[ej[e]];
    }

    // r-weights (L2-hot, identical for all blocks)
    const int j16 = tid & 15, gg = tid >> 4, cb = j16 * 8;
    float wr[6][8], br[8];
#pragma unroll
    for (int q = 0; q < 6; ++q) {
        const float4* p = (const float4*)(W_rbf + q * 128 + cb);
        float4 a = p[0], c = p[1];
        wr[q][0]=a.x; wr[q][1]=a.y; wr[q][2]=a.z; wr[q][3]=a.w;
        wr[q][4]=c.x; wr[q][5]=c.y; wr[q][6]=c.z; wr[q][7]=c.w;
    }
    {
        const float4* p = (const float4*)(b_rbf + cb);
        float4 a = p[0], c = p[1];
        br[0]=a.x; br[1]=a.y; br[2]=a.z; br[3]=a.w;
        br[4]=c.x; br[5]=c.y; br[6]=c.z; br[7]=c.w;
    }

    __syncthreads();   // drains async16 (B + rbf in LDS)

    // ---- phase 1: r-compute from lR -> lA (4 edges x 8 cols per thread) ----
#pragma unroll
    for (int i = 0; i < 4; ++i) {
        int m = gg * 4 + i;
        const float* rr_ = (const float*)(lR + m * 24);
        float f0 = rr_[0], f1 = rr_[1], f2 = rr_[2],
              f3 = rr_[3], f4 = rr_[4], f5 = rr_[5];
        bf16x8 pk;
#pragma unroll
        for (int c = 0; c < 8; ++c) {
            float a = br[c] + f0*wr[0][c] + f1*wr[1][c] + f2*wr[2][c]
                            + f3*wr[3][c] + f4*wr[4][c] + f5*wr[5][c];
            pk[c] = (short)f2bf(silu_f(a));
        }
        int p = j16 ^ (m & 7);
        *(bf16x8*)(lA + m * 256 + p * 16) = pk;
    }

    __syncthreads();

    // ---- phase 2: P prefetch (ushort4, overlaps MFMA), then MFMA ----
    u16x4 q1[2][4], q2[2][4];
#pragma unroll
    for (int mi = 0; mi < 2; ++mi) {
        const unsigned short* p1r = P1 + ti[mi] * 128;
        const unsigned short* p2r = P2 + tj[mi] * 128;
#pragma unroll
        for (int ni = 0; ni < 4; ++ni) {
            int o = wn + ni * 16 + quad * 4;
            q1[mi][ni] = *(const u16x4*)(p1r + o);
            q2[mi][ni] = *(const u16x4*)(p2r + o);
        }
    }

    f32x4 acc[2][4] = {};
    const int l7 = l15 & 7;
#pragma unroll
    for (int ks = 0; ks < 4; ++ks) {
        const int j = ks * 4 + quad;
        const int p = j ^ l7;
        bf16x8 af[2], bfv[4];
#pragma unroll
        for (int mi = 0; mi < 2; ++mi)
            af[mi] = *(const bf16x8*)(lA + (wm + mi * 16 + l15) * 256 + p * 16);
#pragma unroll
        for (int ni = 0; ni < 4; ++ni)
            bfv[ni] = *(const bf16x8*)(lB + (wn + ni * 16 + l15) * 256 + p * 16);
        // swapped operands: D = Wt3_tile . r_tile^T = C^T
        // lane: col = l15 = edge, rows = quad*4+reg = 4 consecutive o
#pragma unroll
        for (int mi = 0; mi < 2; ++mi)
#pragma unroll
            for (int ni = 0; ni < 4; ++ni)
                acc[mi][ni] = __builtin_amdgcn_mfma_f32_16x16x32_bf16(
                    bfv[ni], af[mi], acc[mi][ni], 0, 0, 0);
    }

    // ---- phase 3: epilogue — one edge/lane, float4 nontemporal stores ----
#pragma unroll
    for (int mi = 0; mi < 2; ++mi) {
        size_t e = (size_t)(e0 + wm + mi * 16 + l15);
        float* orow = out + e * 128 + wn;
#pragma unroll
        for (int ni = 0; ni < 4; ++ni) {
            f32x4 v;
#pragma unroll
            for (int r = 0; r < 4; ++r)
                v[r] = silu_f(acc[mi][ni][r]
                              + bf2f(q1[mi][ni][r]) + bf2f(q2[mi][ni][r]));
            __builtin_nontemporal_store(v, (f32x4*)(orow + ni * 16 + quad * 4));
        }
    }
}

extern "C" void kernel_launch(void* const* d_in, const int* in_sizes, int n_in,
                              void* d_out, int out_size, void* d_ws, size_t ws_size,
                              hipStream_t stream) {
    const int*   x        = (const int*)d_in[0];
    const float* rbf      = (const float*)d_in[1];
    const int*   ei       = (const int*)d_in[2];
    const int*   ej       = (const int*)d_in[3];
    const int*   code_idx = (const int*)d_in[4];
    const float* codebook = (const float*)d_in[5];
    const float* W_rbf    = (const float*)d_in[6];
    const float* b_rbf    = (const float*)d_in[7];
    const float* W        = (const float*)d_in[8];
    const float* b        = (const float*)d_in[9];
    float* out = (float*)d_out;

    const int nE = in_sizes[2];                   // 160000

    if (ws_size < 98304) return;                  // P1 + P2 + Wt3, bf16
    unsigned short* P1  = (unsigned short*)d_ws;  // 32 KB
    unsigned short* P2  = P1 + 16384;             // 32 KB
    unsigned short* Wt3 = P2 + 16384;             // 32 KB

    prep_P<<<128, 256, 0, stream>>>(code_idx, codebook, W, b, P1, P2, Wt3);
    fused_main<<<nE / 64, 256, 0, stream>>>(x, rbf, ei, ej, W_rbf, b_rbf,
                                            P1, P2, Wt3, out);
}

// Round 2
// 142.887 us; speedup vs baseline: 1.0503x; 1.0503x over previous
//
#include <hip/hip_runtime.h>
#include <hip/hip_bf16.h>
#include <stdint.h>

typedef __attribute__((ext_vector_type(8))) short bf16x8;
typedef __attribute__((ext_vector_type(4))) float f32x4;
typedef __attribute__((ext_vector_type(4))) unsigned short u16x4;

__device__ __forceinline__ float silu_f(float x) {
    return x * __builtin_amdgcn_rcpf(1.0f + __expf(-x));
}

// round-to-nearest-even f32 -> bf16
__device__ __forceinline__ unsigned short f2bf(float x) {
    union { float f; unsigned int u; } v; v.f = x;
    unsigned int r = v.u + 0x7fffu + ((v.u >> 16) & 1u);
    return (unsigned short)(r >> 16);
}
__device__ __forceinline__ float bf2f(unsigned short u) {
    union { unsigned int u; float f; } v; v.u = ((unsigned int)u) << 16;
    return v.f;
}

// async global->LDS, 16B per lane. LDS dest = wave-uniform base + lane*16.
__device__ __forceinline__ void async16(void* l, const void* g) {
    auto lds3 = (__attribute__((address_space(3))) unsigned int*)(uintptr_t)l;
    auto g1   = (const __attribute__((address_space(1))) unsigned int*)(uintptr_t)g;
    __builtin_amdgcn_global_load_lds(g1, lds3, 16, 0, 0);
}

// Precompute:
//   P1[t][o] = sum_k table[t][k] * W[k][o]       + b[o]   (bf16)
//   P2[t][o] = sum_k table[t][k] * W[128+k][o]            (bf16)
//   Wt3[o][k] = W[256+k][o]                               (bf16, transposed)
__global__ void prep_P(const int* __restrict__ code_idx,
                       const float* __restrict__ codebook,
                       const float* __restrict__ W,
                       const float* __restrict__ b,
                       unsigned short* __restrict__ P1,
                       unsigned short* __restrict__ P2,
                       unsigned short* __restrict__ Wt3)
{
    __shared__ float trow[128];
    const int t = blockIdx.x, tid = threadIdx.x;
    if (tid < 128) {
        int sym = code_idx[t * 8 + (tid >> 4)];
        trow[tid] = codebook[sym * 16 + (tid & 15)];
    } else {
        int k = tid - 128;                       // 0..127
        Wt3[t * 128 + k] = f2bf(W[(256 + k) * 128 + t]);
    }
    __syncthreads();
    const int which = tid >> 7, o = tid & 127;
    const float* Wb = W + which * 16384;
    float acc = which ? 0.0f : b[o];
#pragma unroll 8
    for (int k = 0; k < 128; ++k)
        acc += trow[k] * Wb[k * 128 + o];
    (which ? P2 : P1)[t * 128 + o] = f2bf(acc);
}

// Fused main, 64 edges per block, 256 threads (4 waves, 32x64 C-tile each):
//   lB = Wt3 (128x128 bf16, K=128), async16-staged, chunk-swizzled
//   lR = rbf tile (64 x 24B), async16-staged
//   lA = r = silu(rbf @ W_rbf + b_rbf) bf16, VALU-computed from lR
//   C^T = B @ A^T via SWAPPED mfma operands (A/B operand layouts are
//   symmetric, so swapping args transposes D): each lane then owns one
//   edge x 4 consecutive output cols per tile -> float4 stores, ushort4
//   P-gathers, 4x fewer VMEM instructions in the epilogue.
//   Stores are PLAIN (cached): 82MB output fits the 256MB L3; nontemporal
//   stores forced a synchronous 108MB HBM drain at ~2 TB/s (round-1
//   regression, WRITE_SIZE 108MB -> kernel 55us write-bound).
__global__ __launch_bounds__(256, 3) void fused_main(
    const int* __restrict__ x,
    const float* __restrict__ rbf,
    const int* __restrict__ ei,
    const int* __restrict__ ej,
    const float* __restrict__ W_rbf,
    const float* __restrict__ b_rbf,
    const unsigned short* __restrict__ P1,
    const unsigned short* __restrict__ P2,
    const unsigned short* __restrict__ Wt3,
    float* __restrict__ out)
{
    __shared__ __align__(16) unsigned char lB[32768];  // Wt3 [128 rows][256B]
    __shared__ __align__(16) unsigned char lA[16384];  // r   [64 rows][256B]
    __shared__ __align__(16) unsigned char lR[1536];   // rbf [64 rows][24B]

    const int tid  = threadIdx.x;
    const int lane = tid & 63;
    const int w    = tid >> 6;
    const int e0   = blockIdx.x * 64;

    const int quad = lane >> 4, l15 = lane & 15;
    const int wm = (w >> 1) * 32, wn = (w & 1) * 64;

    // ---- phase 0: async stages + index chase ----
    {   // B: physical chunk ch holds logical chunk ch ^ (o&7)
        const int ri = lane >> 4, ch = lane & 15;
#pragma unroll
        for (int rr = 0; rr < 8; ++rr) {
            int g = w * 8 + rr;           // 4-row group 0..31
            int o = g * 4 + ri;
            int j = ch ^ (o & 7);
            async16(lB + g * 1024, Wt3 + o * 128 + j * 8);
        }
    }
    // rbf tile: 1536B contiguous
    if (w == 0)
        async16(lR, (const unsigned char*)rbf + (size_t)e0 * 24 + lane * 16);
    else if (w == 1 && lane < 32)
        async16(lR + 1024, (const unsigned char*)rbf + (size_t)e0 * 24 + 1024 + lane * 16);

    // epilogue row indices: lane (l15) owns edge wm+mi*16+l15 (same for all
    // quads) -> only 2 chases per thread per table
    int ti[2], tj[2];
#pragma unroll
    for (int mi = 0; mi < 2; ++mi) {
        int e = e0 + wm + mi * 16 + l15;
        ti[mi] = x[ei[e]];
        tj[mi] = x[ej[e]];
    }

    // r-weights (L2-hot, identical for all blocks)
    const int j16 = tid & 15, gg = tid >> 4, cb = j16 * 8;
    float wr[6][8], br[8];
#pragma unroll
    for (int q = 0; q < 6; ++q) {
        const float4* p = (const float4*)(W_rbf + q * 128 + cb);
        float4 a = p[0], c = p[1];
        wr[q][0]=a.x; wr[q][1]=a.y; wr[q][2]=a.z; wr[q][3]=a.w;
        wr[q][4]=c.x; wr[q][5]=c.y; wr[q][6]=c.z; wr[q][7]=c.w;
    }
    {
        const float4* p = (const float4*)(b_rbf + cb);
        float4 a = p[0], c = p[1];
        br[0]=a.x; br[1]=a.y; br[2]=a.z; br[3]=a.w;
        br[4]=c.x; br[5]=c.y; br[6]=c.z; br[7]=c.w;
    }

    __syncthreads();   // drains async16 (B + rbf in LDS)

    // ---- phase 1: r-compute from lR -> lA (4 edges x 8 cols per thread) ----
#pragma unroll
    for (int i = 0; i < 4; ++i) {
        int m = gg * 4 + i;
        const float* rr_ = (const float*)(lR + m * 24);
        float f0 = rr_[0], f1 = rr_[1], f2 = rr_[2],
              f3 = rr_[3], f4 = rr_[4], f5 = rr_[5];
        bf16x8 pk;
#pragma unroll
        for (int c = 0; c < 8; ++c) {
            float a = br[c] + f0*wr[0][c] + f1*wr[1][c] + f2*wr[2][c]
                            + f3*wr[3][c] + f4*wr[4][c] + f5*wr[5][c];
            pk[c] = (short)f2bf(silu_f(a));
        }
        int p = j16 ^ (m & 7);
        *(bf16x8*)(lA + m * 256 + p * 16) = pk;
    }

    __syncthreads();

    // ---- phase 2: P prefetch (ushort4, overlaps MFMA), then MFMA ----
    u16x4 q1[2][4], q2[2][4];
#pragma unroll
    for (int mi = 0; mi < 2; ++mi) {
        const unsigned short* p1r = P1 + ti[mi] * 128;
        const unsigned short* p2r = P2 + tj[mi] * 128;
#pragma unroll
        for (int ni = 0; ni < 4; ++ni) {
            int o = wn + ni * 16 + quad * 4;
            q1[mi][ni] = *(const u16x4*)(p1r + o);
            q2[mi][ni] = *(const u16x4*)(p2r + o);
        }
    }

    f32x4 acc[2][4] = {};
    const int l7 = l15 & 7;
#pragma unroll
    for (int ks = 0; ks < 4; ++ks) {
        const int j = ks * 4 + quad;
        const int p = j ^ l7;
        bf16x8 af[2], bfv[4];
#pragma unroll
        for (int mi = 0; mi < 2; ++mi)
            af[mi] = *(const bf16x8*)(lA + (wm + mi * 16 + l15) * 256 + p * 16);
#pragma unroll
        for (int ni = 0; ni < 4; ++ni)
            bfv[ni] = *(const bf16x8*)(lB + (wn + ni * 16 + l15) * 256 + p * 16);
        // swapped operands: D = Wt3_tile . r_tile^T = C^T
        // lane: col = l15 = edge, rows = quad*4+reg = 4 consecutive o
#pragma unroll
        for (int mi = 0; mi < 2; ++mi)
#pragma unroll
            for (int ni = 0; ni < 4; ++ni)
                acc[mi][ni] = __builtin_amdgcn_mfma_f32_16x16x32_bf16(
                    bfv[ni], af[mi], acc[mi][ni], 0, 0, 0);
    }

    // ---- phase 3: epilogue — one edge/lane, float4 cached stores ----
#pragma unroll
    for (int mi = 0; mi < 2; ++mi) {
        size_t e = (size_t)(e0 + wm + mi * 16 + l15);
        float* orow = out + e * 128 + wn;
#pragma unroll
        for (int ni = 0; ni < 4; ++ni) {
            f32x4 v;
#pragma unroll
            for (int r = 0; r < 4; ++r)
                v[r] = silu_f(acc[mi][ni][r]
                              + bf2f(q1[mi][ni][r]) + bf2f(q2[mi][ni][r]));
            *(f32x4*)(orow + ni * 16 + quad * 4) = v;
        }
    }
}

extern "C" void kernel_launch(void* const* d_in, const int* in_sizes, int n_in,
                              void* d_out, int out_size, void* d_ws, size_t ws_size,
                              hipStream_t stream) {
    const int*   x        = (const int*)d_in[0];
    const float* rbf      = (const float*)d_in[1];
    const int*   ei       = (const int*)d_in[2];
    const int*   ej       = (const int*)d_in[3];
    const int*   code_idx = (const int*)d_in[4];
    const float* codebook = (const float*)d_in[5];
    const float* W_rbf    = (const float*)d_in[6];
    const float* b_rbf    = (const float*)d_in[7];
    const float* W        = (const float*)d_in[8];
    const float* b        = (const float*)d_in[9];
    float* out = (float*)d_out;

    const int nE = in_sizes[2];                   // 160000

    if (ws_size < 98304) return;                  // P1 + P2 + Wt3, bf16
    unsigned short* P1  = (unsigned short*)d_ws;  // 32 KB
    unsigned short* P2  = P1 + 16384;             // 32 KB
    unsigned short* Wt3 = P2 + 16384;             // 32 KB

    prep_P<<<128, 256, 0, stream>>>(code_idx, codebook, W, b, P1, P2, Wt3);
    fused_main<<<nE / 64, 256, 0, stream>>>(x, rbf, ei, ej, W_rbf, b_rbf,
                                            P1, P2, Wt3, out);
}